// Round 19
// baseline (154.336 us; speedup 1.0000x reference)
//
#include <hip/hip_runtime.h>
#include <hip/hip_bf16.h>

// Round 31: k_ygemm 2-phase double-buffer prefetch (guide T3 minimum-2-phase).
// r29/r30 measured NEUTRAL (150.0 fast-chip vs r27 151.9 slow-chip) ->
// GEMM staging throughput not the mass; k_fused GEMM latency already hidden
// by co-resident occupancy blocks (r27 overlap). The latency-EXPOSED kernel
// is k_ygemm: 256 blocks = 1 wave/SIMD, 32 K-steps x 2 drain-barriers, no
// TLP cover. Fix: dbuf LDS (24KB), issue next-tile gload_lds BEFORE current
// compute, ONE barrier per K-step. Same staged values / MFMA order ->
// y bit-identical, stats adds identical -> absmax unchanged.
// Everything else identical to r29 (gload_lds kept: fewer insts, no cost).
//
// ws (floats): conv 0..9216 (Wenc0 benc1024 bdec2048 wful3072 bout4096
//   bmlp5120 gam6144 bet7168 w0 8192) | occ@9216(131072) | stats@140288(2048)
//   | P1@142336(2097152)
// bf16 u0=(ushort*)(ws+2239488): hbf0 WdecT@131072 WoutT@196608 WmlpT@294912
//   Xcat0@1343488 y_mf@1540096..3637248   (~16.2 MB)
// hd / pool staged in d_out (validated; rewritten by k_norm).

#define NG2  64
#define NPTS 4096

typedef unsigned short ushort_t;
typedef __attribute__((ext_vector_type(8))) short bf16x8;
typedef __attribute__((ext_vector_type(4))) float f32x4;

struct PrepPtrs { const void* p[16]; };

__device__ __forceinline__ float bf2f(ushort_t u) {
  return __uint_as_float(((unsigned int)u) << 16);
}
__device__ __forceinline__ ushort_t f2bf(float f) {
  __hip_bfloat16 b = __float2bfloat16(f);
  return *reinterpret_cast<ushort_t*>(&b);
}
__device__ __forceinline__ float lde(const void* p, size_t i, int fl) {
  return fl ? bf2f(((const ushort_t*)p)[i]) : ((const float*)p)[i];
}
__device__ __forceinline__ int block_flag(const ushort_t* h) {
  __shared__ int bad_sh;
  if (threadIdx.x == 0) bad_sh = 0;
  __syncthreads();
  float v = bf2f(h[threadIdx.x & 255]);
  if (!(fabsf(v) <= 1e4f)) atomicOr(&bad_sh, 1);
  __syncthreads();
  return (bad_sh == 0) ? 1 : 0;
}
// async 16B global->LDS (dest must be linear in tid order within the wave)
__device__ __forceinline__ void gload16(const ushort_t* g, ushort_t* l) {
  __builtin_amdgcn_global_load_lds(
      (const __attribute__((address_space(1))) unsigned int*)g,
      (__attribute__((address_space(3))) unsigned int*)l, 16, 0, 0);
}

// ---------------------------------------------------------------- prep (426 blocks)
// sections: [0,9)convert  [9,73)h2b  [73,137)tpWdec  [137,233)tpWout'
// [233,425)Xcat0  [425]stats0
__device__ __forceinline__ void tp_body(const void* in, int fl, int job,
                                        int Kin, int Kpad, ushort_t* out) {
  __shared__ ushort_t t[32][40];
  int n0 = (job & 31) * 32, k0 = (job >> 5) * 32;
  int r = threadIdx.x >> 3, c4 = (threadIdx.x & 7) * 4;
  ushort4 v = make_ushort4(0, 0, 0, 0);
  if (k0 + r < Kin) {
    size_t off = (size_t)(k0 + r) * 1024 + n0 + c4;
    if (fl) {
      v = *(const ushort4*)((const ushort_t*)in + off);
    } else {
      float4 f = *(const float4*)((const float*)in + off);
      v = make_ushort4(f2bf(f.x), f2bf(f.y), f2bf(f.z), f2bf(f.w));
    }
  }
  *(ushort4*)(&t[r][c4]) = v;
  __syncthreads();
  int n = threadIdx.x >> 3, kk = (threadIdx.x & 7) * 4;
  ushort4 o = make_ushort4(t[kk][n], t[kk + 1][n], t[kk + 2][n], t[kk + 3][n]);
  *(ushort4*)(out + (size_t)(n0 + n) * Kpad + k0 + kk) = o;
}

__global__ __launch_bounds__(256) void k_prep(PrepPtrs ptrs,
                                              float* __restrict__ conv,
                                              ushort_t* __restrict__ hbf,
                                              ushort_t* __restrict__ WdecT,
                                              ushort_t* __restrict__ WoutT,
                                              ushort_t* __restrict__ Xcat0,
                                              float* __restrict__ stats) {
  int b = blockIdx.x;
  int fl = block_flag((const ushort_t*)ptrs.p[0]);
  if (b < 9) {
    // 9 segments x 1024 floats: Wenc benc bdec wful bout bmlp gam bet w0
    int idx = (b * 256 + threadIdx.x) * 4;
    int seg = idx >> 10, off = idx & 1023;
    float4 o;
    if (fl) {
      const unsigned int* src = (const unsigned int*)ptrs.p[7 + seg];
      uint2 u = *(const uint2*)(src + (off >> 1));
      o.x = __uint_as_float((u.x & 0xFFFFu) << 16);
      o.y = __uint_as_float(u.x & 0xFFFF0000u);
      o.z = __uint_as_float((u.y & 0xFFFFu) << 16);
      o.w = __uint_as_float(u.y & 0xFFFF0000u);
    } else {
      o = *(const float4*)((const float*)ptrs.p[7 + seg] + off);
    }
    *(float4*)(conv + idx) = o;
  } else if (b < 73) {
    // h -> bf16, 16384 chunks of 8 elems, 64 blocks
    int i = (b - 9) * 256 + threadIdx.x;
    if (fl) {
      ((uint4*)hbf)[i] = ((const uint4*)ptrs.p[0])[i];
    } else {
      float4 f0 = ((const float4*)ptrs.p[0])[2 * i];
      float4 f1 = ((const float4*)ptrs.p[0])[2 * i + 1];
      ((ushort4*)hbf)[2 * i]     = make_ushort4(f2bf(f0.x), f2bf(f0.y), f2bf(f0.z), f2bf(f0.w));
      ((ushort4*)hbf)[2 * i + 1] = make_ushort4(f2bf(f1.x), f2bf(f1.y), f2bf(f1.z), f2bf(f1.w));
    }
  } else if (b < 137) {
    tp_body(ptrs.p[1], fl, b - 73, 64, 64, WdecT);
  } else if (b < 233) {
    const void* wout1 = fl ? (const void*)((const ushort_t*)ptrs.p[2] + 1024)
                           : (const void*)((const float*)ptrs.p[2] + 1024);
    tp_body(wout1, fl, b - 137, 68, 96, WoutT);
  } else if (b < 425) {
    int flat = (b - 233) * 256 + threadIdx.x;   // 49152 ushort4 items
    int e4 = flat * 4;
    int r = e4 / 96, c = e4 - r * 96;
    ushort4 v = make_ushort4(0, 0, 0, 0);
    if (c < 64) {
      if (fl) v = *(const ushort4*)((const ushort_t*)ptrs.p[0] + r * 64 + c);
      else {
        float4 f = *(const float4*)((const float*)ptrs.p[0] + r * 64 + c);
        v = make_ushort4(f2bf(f.x), f2bf(f.y), f2bf(f.z), f2bf(f.w));
      }
    } else if (c == 64) {
      v.x = f2bf(lde(ptrs.p[4], 2 * r, fl));      // end x
      v.y = f2bf(lde(ptrs.p[4], 2 * r + 1, fl));  // end y
      v.z = f2bf(lde(ptrs.p[5], 2 * r, fl));      // rel x
      v.w = f2bf(lde(ptrs.p[5], 2 * r + 1, fl));  // rel y
    }
    *(ushort4*)(Xcat0 + e4) = v;
  } else {
#pragma unroll
    for (int k = 0; k < 8; k++) stats[threadIdx.x + 256 * k] = 0.0f;
  }
}

// ---------------------------------------------------------------- MFMA GEMM body (64x128, gload_lds)
// EPI0: bf16(acc + b1 + b2) ; EPI3: f32 acc + b1
template <int K, int EPI>
__device__ __forceinline__ void mgemm_body(
    ushort_t* As, ushort_t* Bs, int m0, int n0,
    const ushort_t* __restrict__ A, int lda,
    const ushort_t* __restrict__ BT, int ldb,
    const float* __restrict__ bias1, const float* __restrict__ bias2,
    ushort_t* __restrict__ outb, float* __restrict__ outf) {
  int tid = threadIdx.x;
  int wave = tid >> 6, lane = tid & 63, l15 = lane & 15, kg = lane >> 4;
  f32x4 acc[4][2] = {};
  int ar = tid >> 2, ag = tid & 3;
  int agS = ag ^ ((ar >> 1) & 3);          // pre-swizzled global k-group
  int br1 = (tid + 256) >> 2, bg1 = (tid + 256) & 3;
  int bg1S = bg1 ^ ((br1 >> 1) & 3);
  for (int k0 = 0; k0 < K; k0 += 32) {
    gload16(A + (size_t)(m0 + ar) * lda + k0 + agS * 8, &As[tid * 8]);
    gload16(BT + (size_t)(n0 + ar) * ldb + k0 + agS * 8, &Bs[tid * 8]);
    gload16(BT + (size_t)(n0 + br1) * ldb + k0 + bg1S * 8, &Bs[(tid + 256) * 8]);
    __syncthreads();
    bf16x8 af[4], bfr[2];
#pragma unroll
    for (int mt = 0; mt < 4; mt++) {
      int row = mt * 16 + l15;
      int swz = kg ^ ((row >> 1) & 3);
      af[mt] = *(const bf16x8*)(&As[row * 32 + swz * 8]);
    }
#pragma unroll
    for (int nt = 0; nt < 2; nt++) {
      int row = wave * 32 + nt * 16 + l15;
      int swz = kg ^ ((row >> 1) & 3);
      bfr[nt] = *(const bf16x8*)(&Bs[row * 32 + swz * 8]);
    }
#pragma unroll
    for (int mt = 0; mt < 4; mt++)
#pragma unroll
      for (int nt = 0; nt < 2; nt++)
        acc[mt][nt] = __builtin_amdgcn_mfma_f32_16x16x32_bf16(af[mt], bfr[nt], acc[mt][nt], 0, 0, 0);
    __syncthreads();
  }
#pragma unroll
  for (int nt = 0; nt < 2; nt++) {
    int col = n0 + wave * 32 + nt * 16 + l15;
    float bsum = (EPI == 0) ? (bias1[col] + bias2[col]) : bias1[col];
#pragma unroll
    for (int mt = 0; mt < 4; mt++) {
#pragma unroll
      for (int r = 0; r < 4; r++) {
        int rowm = m0 + mt * 16 + kg * 4 + r;
        float v = acc[mt][nt][r] + bsum;
        if (EPI == 3) outf[(size_t)rowm * 1024 + col] = v;
        else outb[(size_t)rowm * 1024 + col] = f2bf(v);
      }
    }
  }
}

// ---------------------------------------------------------------- fused GEMM2 + occupancy + WmlpT
// [0,512) GEMM | [512,2560) occupancy ped | [2560,2816) WmlpT transpose.
__global__ __launch_bounds__(256) void k_fused(
    PrepPtrs ptrs,
    const ushort_t* __restrict__ hbf, const ushort_t* __restrict__ WdecT,
    const float* __restrict__ benc, const float* __restrict__ bdec,
    ushort_t* __restrict__ hd_out,
    const ushort_t* __restrict__ Xcat0, const ushort_t* __restrict__ WoutT,
    const float* __restrict__ bout, float* __restrict__ P1,
    ushort_t* __restrict__ WmlpT, float* __restrict__ occ) {
  __shared__ __align__(16) char smem_raw[12288];
  int b = blockIdx.x;
  if (b < 512) {
    ushort_t* As = (ushort_t*)smem_raw;              // 4096 B
    ushort_t* Bs = (ushort_t*)(smem_raw + 4096);     // 8192 B
    int bb = b & 255;
    int m0 = (bb & 31) * 64, n0 = ((bb >> 5) & 7) * 128;
    if (b < 256)
      mgemm_body<64, 0>(As, Bs, m0, n0, hbf, 64, WdecT, 64, benc, bdec, hd_out, nullptr);
    else
      mgemm_body<96, 3>(As, Bs, m0, n0, Xcat0, 96, WoutT, 96, bout, nullptr, nullptr, P1);
  } else if (b < 2560) {
    // occupancy: block per pedestrian (r12-validated body)
    int fl = block_flag((const ushort_t*)ptrs.p[0]);
    int i = b - 512;
    int s = i >> 6;
    float* cnth = (float*)smem_raw;
    if (threadIdx.x < NG2) cnth[threadIdx.x] = 0.0f;
    __syncthreads();
    float ex = lde(ptrs.p[4], 2 * i, fl), ey = lde(ptrs.p[4], 2 * i + 1, fl);
    float tlx = ex - 1.0f, tly = ey + 1.0f, brx = ex + 1.0f, bry = ey - 1.0f;
    const void* scn = ptrs.p[6];
    for (int p = threadIdx.x; p < NPTS; p += 256) {
      size_t pi = (size_t)s * NPTS + p;
      float sx, sy;
      if (fl) {
        unsigned int u = ((const unsigned int*)scn)[pi];
        sx = __uint_as_float((u & 0xFFFFu) << 16);
        sy = __uint_as_float(u & 0xFFFF0000u);
      } else {
        float2 f = *((const float2*)scn + pi);
        sx = f.x; sy = f.y;
      }
      bool oob = (sx >= brx) || (sx <= tlx) || (sy >= tly) || (sy <= bry);
      if (!oob) {
        int cx = (int)floorf((sx - tlx) * 0.5f * 8.0f);
        int cy = (int)floorf((tly - sy) * 0.5f * 8.0f);
        int cell = cx + cy * 8;
        if (cell >= 0 && cell < NG2) atomicAdd(&cnth[cell], 1.0f);
      }
    }
    __syncthreads();
    if (threadIdx.x < NG2) occ[(size_t)i * NG2 + threadIdx.x] = cnth[threadIdx.x];
  } else {
    // W_mlp 1024x1024 -> WmlpT bf16, 64x64 tiles (r13-validated body)
    int fl = block_flag((const ushort_t*)ptrs.p[0]);
    ushort_t* t64 = (ushort_t*)smem_raw;             // 64*68*2 = 8704 B
    int job = b - 2560;
    int n0 = (job & 15) * 64, k0 = (job >> 4) * 64;
    const void* in = ptrs.p[3];
#pragma unroll
    for (int i = 0; i < 4; i++) {
      int chunk = threadIdx.x + i * 256;
      int r = chunk >> 4, c4 = (chunk & 15) * 4;
      ushort4 v;
      size_t off = (size_t)(k0 + r) * 1024 + n0 + c4;
      if (fl) {
        v = *(const ushort4*)((const ushort_t*)in + off);
      } else {
        float4 f = *(const float4*)((const float*)in + off);
        v = make_ushort4(f2bf(f.x), f2bf(f.y), f2bf(f.z), f2bf(f.w));
      }
      *(ushort4*)(&t64[r * 68 + c4]) = v;
    }
    __syncthreads();
#pragma unroll
    for (int i = 0; i < 4; i++) {
      int chunk = threadIdx.x + i * 256;
      int n = chunk >> 4, k4 = (chunk & 15) * 4;
      ushort4 o = make_ushort4(t64[(k4 + 0) * 68 + n], t64[(k4 + 1) * 68 + n],
                               t64[(k4 + 2) * 68 + n], t64[(k4 + 3) * 68 + n]);
      *(ushort4*)(WmlpT + (size_t)(n0 + n) * 1024 + k0 + k4) = o;
    }
  }
}

// ---------------------------------------------------------------- y GEMM 64x128, 2-phase dbuf (r31)
// T3 minimum-2-phase: prologue-stage buf0; per K-step issue STAGE(next,buf^1)
// async, then ds_read+MFMA(cur), then ONE barrier (drains vmcnt + protects
// buf[cur] reads before next overwrite). 32 barriers instead of 64, loads
// overlap compute. Same values/order -> y bit-identical.
__global__ __launch_bounds__(256) void k_ygemm(
    const ushort_t* __restrict__ A, const ushort_t* __restrict__ BT,
    const float* __restrict__ bias1, ushort_t* __restrict__ outb,
    float* __restrict__ stats) {
  __shared__ ushort_t As[2][64 * 32];
  __shared__ ushort_t Bs[2][128 * 32];
  int m0 = blockIdx.x * 64, n0 = blockIdx.y * 128;
  int tid = threadIdx.x;
  int wave = tid >> 6, lane = tid & 63, l15 = lane & 15, kg = lane >> 4;
  f32x4 acc[4][2] = {};
  int ar = tid >> 2, ag = tid & 3;
  int agS = ag ^ ((ar >> 1) & 3);
  int br1 = (tid + 256) >> 2, bg1 = (tid + 256) & 3;
  int bg1S = bg1 ^ ((br1 >> 1) & 3);
  const ushort_t* arow = A + (size_t)(m0 + ar) * 1024 + agS * 8;
  const ushort_t* brow0 = BT + (size_t)(n0 + ar) * 1024 + agS * 8;
  const ushort_t* brow1 = BT + (size_t)(n0 + br1) * 1024 + bg1S * 8;
  // prologue: stage k0=0 into buffer 0
  gload16(arow, &As[0][tid * 8]);
  gload16(brow0, &Bs[0][tid * 8]);
  gload16(brow1, &Bs[0][(tid + 256) * 8]);
  __syncthreads();
  int cur = 0;
  for (int t = 0; t < 32; ++t) {
    if (t < 31) {
      int k0n = (t + 1) * 32;
      gload16(arow + k0n, &As[cur ^ 1][tid * 8]);
      gload16(brow0 + k0n, &Bs[cur ^ 1][tid * 8]);
      gload16(brow1 + k0n, &Bs[cur ^ 1][(tid + 256) * 8]);
    }
    bf16x8 af[4], bfr[2];
#pragma unroll
    for (int mt = 0; mt < 4; mt++) {
      int row = mt * 16 + l15;
      int swz = kg ^ ((row >> 1) & 3);
      af[mt] = *(const bf16x8*)(&As[cur][row * 32 + swz * 8]);
    }
#pragma unroll
    for (int nt = 0; nt < 2; nt++) {
      int row = wave * 32 + nt * 16 + l15;
      int swz = kg ^ ((row >> 1) & 3);
      bfr[nt] = *(const bf16x8*)(&Bs[cur][row * 32 + swz * 8]);
    }
#pragma unroll
    for (int mt = 0; mt < 4; mt++)
#pragma unroll
      for (int nt = 0; nt < 2; nt++)
        acc[mt][nt] = __builtin_amdgcn_mfma_f32_16x16x32_bf16(af[mt], bfr[nt], acc[mt][nt], 0, 0, 0);
    __syncthreads();
    cur ^= 1;
  }
#pragma unroll
  for (int nt = 0; nt < 2; nt++) {
    int col = n0 + wave * 32 + nt * 16 + l15;
    float bsum = bias1[col];
    float s1 = 0.0f, s2 = 0.0f;
#pragma unroll
    for (int mt = 0; mt < 4; mt++) {
#pragma unroll
      for (int r = 0; r < 4; r++) {
        int rowm = m0 + mt * 16 + kg * 4 + r;
        float v = acc[mt][nt][r] + bsum;
        outb[(size_t)rowm * 1024 + col] = f2bf(v);
        s1 += v; s2 = fmaf(v, v, s2);
      }
    }
    s1 += __shfl_down(s1, 16); s2 += __shfl_down(s2, 16);
    s1 += __shfl_down(s1, 32); s2 += __shfl_down(s2, 32);
    if (lane < 16) {
      atomicAdd(&stats[col], s1);
      atomicAdd(&stats[1024 + col], s2);
    }
  }
}

// ---------------------------------------------------------------- ectx (shuffle-free e-phase)
__global__ __launch_bounds__(256) void k_ectx(
    const float* __restrict__ occ,
    const float* __restrict__ Wenc, const float* __restrict__ wfull,
    const float* __restrict__ w0, const float* __restrict__ P1,
    const ushort_t* __restrict__ hd, ushort_t* __restrict__ pool) {
  __shared__ float we_sh[1024];
  __shared__ float wf_sh[1024];
  __shared__ float hd_sh[4][1024];
  __shared__ float occ_sh[4][64];
  int wave = threadIdx.x >> 6, lane = threadIdx.x & 63;
  int p = blockIdx.x * 4 + wave;
  // cooperative stage of Wenc / wfull (256 threads x float4)
  {
    int t = threadIdx.x * 4;
    *(float4*)&we_sh[t] = *(const float4*)(Wenc + t);
    *(float4*)&wf_sh[t] = *(const float4*)(wfull + t);
  }
  occ_sh[wave][lane] = occ[p * 64 + lane];
  // stage hd row bf16 -> f32 (coalesced: 1KB per wave per j)
  {
    const ushort_t* hrow = hd + (size_t)p * 1024;
#pragma unroll
    for (int j = 0; j < 4; j++) {
      int a = lane * 4 + j * 256;
      ushort4 v = *(const ushort4*)(hrow + a);
      hd_sh[wave][a + 0] = bf2f(v.x);
      hd_sh[wave][a + 1] = bf2f(v.y);
      hd_sh[wave][a + 2] = bf2f(v.z);
      hd_sh[wave][a + 3] = bf2f(v.w);
    }
  }
  __syncthreads();
  // lane g = lane computes e[p,g] privately: broadcast LDS reads, no shuffles
  float c = occ_sh[wave][lane];
  float s0 = 0.0f, s1 = 0.0f, s2 = 0.0f, s3 = 0.0f;
#pragma unroll 4
  for (int a = 0; a < 1024; a += 4) {
    float4 we4 = *(const float4*)&we_sh[a];
    float4 hd4 = *(const float4*)&hd_sh[wave][a];
    float4 wf4 = *(const float4*)&wf_sh[a];
    s0 += fmaxf(fmaf(c, we4.x, hd4.x), 0.0f) * wf4.x;
    s1 += fmaxf(fmaf(c, we4.y, hd4.y), 0.0f) * wf4.y;
    s2 += fmaxf(fmaf(c, we4.z, hd4.z), 0.0f) * wf4.z;
    s3 += fmaxf(fmaf(c, we4.w, hd4.w), 0.0f) * wf4.w;
  }
  float e_mine = (s0 + s1) + (s2 + s3);
  // softmax over g (the only cross-lane phase left)
  float m = e_mine;
#pragma unroll
  for (int off = 32; off > 0; off >>= 1) m = fmaxf(m, __shfl_xor(m, off));
  float xe = __expf(e_mine - m);
  float den = xe;
#pragma unroll
  for (int off = 32; off > 0; off >>= 1) den += __shfl_xor(den, off);
  float cp = xe * c;
#pragma unroll
  for (int off = 32; off > 0; off >>= 1) cp += __shfl_xor(cp, off);
  float ctx = cp / den;
#pragma unroll
  for (int j = 0; j < 16; j++) {
    int a = lane + j * 64;
    pool[(size_t)p * 1024 + a] = f2bf(fmaf(ctx, w0[a], P1[(size_t)p * 1024 + a]));
  }
}

// ---------------------------------------------------------------- batchnorm+relu (validated)
__global__ void k_norm(const ushort_t* __restrict__ y_mf,
                       const float* __restrict__ stats,
                       const float* __restrict__ gamma, const float* __restrict__ beta,
                       const ushort_t* __restrict__ hsrc, void* __restrict__ out) {
  int fl = block_flag(hsrc);
  int idx = (blockIdx.x * 256 + threadIdx.x) * 4;
  int col = idx & 1023;
  float vv[4];
#pragma unroll
  for (int j = 0; j < 4; j++) vv[j] = bf2f(y_mf[idx + j]);
  float4 s1 = *(const float4*)(stats + col);
  float4 s2 = *(const float4*)(stats + 1024 + col);
  float4 gm = *(const float4*)(gamma + col);
  float4 bt = *(const float4*)(beta + col);
  const float ib = 1.0f / 2048.0f;
  float m1[4] = {s1.x, s1.y, s1.z, s1.w};
  float m2[4] = {s2.x, s2.y, s2.z, s2.w};
  float gg[4] = {gm.x, gm.y, gm.z, gm.w};
  float bb[4] = {bt.x, bt.y, bt.z, bt.w};
  float o[4];
#pragma unroll
  for (int j = 0; j < 4; j++) {
    float mu = m1[j] * ib;
    float var = fmaf(-mu, mu, m2[j] * ib);
    o[j] = fmaxf(fmaf(gg[j] * (vv[j] - mu), rsqrtf(var + 1e-5f), bb[j]), 0.0f);
  }
  if (fl) {
    ushort4 ov = make_ushort4(f2bf(o[0]), f2bf(o[1]), f2bf(o[2]), f2bf(o[3]));
    *(ushort4*)((ushort_t*)out + idx) = ov;
  } else {
    *(float4*)((float*)out + idx) = make_float4(o[0], o[1], o[2], o[3]);
  }
}

// ---------------------------------------------------------------- launch
extern "C" void kernel_launch(void* const* d_in, const int* in_sizes, int n_in,
                              void* d_out, int out_size, void* d_ws, size_t ws_size,
                              hipStream_t stream) {
  float* ws = (float*)d_ws;
  float* conv   = ws;
  float* c_Wenc = conv + 0;
  float* c_benc = conv + 1024;
  float* c_bdec = conv + 2048;
  float* c_wful = conv + 3072;
  float* c_bout = conv + 4096;
  float* c_bmlp = conv + 5120;
  float* c_gam  = conv + 6144;
  float* c_bet  = conv + 7168;
  float* c_w0   = conv + 8192;
  float* occ    = ws + 9216;
  float* stats  = ws + 140288;
  float* P1     = ws + 142336;
  ushort_t* u0    = (ushort_t*)(ws + 2239488);
  ushort_t* hbf   = u0;
  ushort_t* WdecT = u0 + 131072;
  ushort_t* WoutT = u0 + 196608;
  ushort_t* WmlpT = u0 + 294912;
  ushort_t* Xcat0 = u0 + 1343488;
  ushort_t* y_mf  = u0 + 1540096;
  ushort_t* hd_bf   = (ushort_t*)d_out;   // validated d_out-as-scratch
  ushort_t* pool_mf = (ushort_t*)d_out;

  PrepPtrs ptrs;
  ptrs.p[0] = d_in[0];   // h (flag, h2b, Xcat0)
  ptrs.p[1] = d_in[6];   // W_dec (tp)
  ptrs.p[2] = d_in[10];  // W_out (tp rows 1..68)
  ptrs.p[3] = d_in[12];  // W_mlp (tp 64x64, in k_fused)
  ptrs.p[4] = d_in[1];   // end_pos (Xcat0, occupancy)
  ptrs.p[5] = d_in[2];   // rel_pos (Xcat0)
  ptrs.p[6] = d_in[3];   // scene (occupancy)
  ptrs.p[7]  = d_in[4];  // W_enc  (conv seg0)
  ptrs.p[8]  = d_in[5];  // b_enc  (seg1)
  ptrs.p[9]  = d_in[7];  // b_dec  (seg2)
  ptrs.p[10] = d_in[8];  // w_full (seg3)
  ptrs.p[11] = d_in[11]; // b_out  (seg4)
  ptrs.p[12] = d_in[13]; // b_mlp  (seg5)
  ptrs.p[13] = d_in[14]; // gamma  (seg6)
  ptrs.p[14] = d_in[15]; // beta   (seg7)
  ptrs.p[15] = d_in[10]; // w0 = W_out row 0 (seg8)

  k_prep<<<426, 256, 0, stream>>>(ptrs, conv, hbf, WdecT, WoutT, Xcat0, stats);

  k_fused<<<2816, 256, 0, stream>>>(ptrs, hbf, WdecT, c_benc, c_bdec, hd_bf,
                                    Xcat0, WoutT, c_bout, P1, WmlpT, occ);

  k_ectx<<<512, 256, 0, stream>>>(occ, c_Wenc, c_wful, c_w0, P1, hd_bf, pool_mf);

  k_ygemm<<<dim3(32, 8), 256, 0, stream>>>(pool_mf, WmlpT, c_bmlp, y_mf, stats);

  k_norm<<<2048, 256, 0, stream>>>(y_mf, stats, c_gam, c_bet,
                                   (const ushort_t*)d_in[0], d_out);
}

// Round 24
// 149.390 us; speedup vs baseline: 1.0331x; 1.0331x over previous
//
#include <hip/hip_runtime.h>
#include <hip/hip_bf16.h>

// Round 36 == Round 32 resubmitted (4x GPU acquisition timeout; never ran).
// (a) REVERT r31 2-phase dbuf in k_ygemm (+4us regression measured;
// consistent with guide m99/m100: barrier vmcnt(0) drain makes source-level
// dbuf structural-neutral-at-best). Back to r29 single-buffer gload_lds form
// (150.0us best). (b) occupancy scene loads vectorized: 2 points per load
// (float4/uint2), 16->8 iters/thread. Same exact +1.0f adds -> absmax same.
//
// ws (floats): conv 0..9216 (Wenc0 benc1024 bdec2048 wful3072 bout4096
//   bmlp5120 gam6144 bet7168 w0 8192) | occ@9216(131072) | stats@140288(2048)
//   | P1@142336(2097152)
// bf16 u0=(ushort*)(ws+2239488): hbf0 WdecT@131072 WoutT@196608 WmlpT@294912
//   Xcat0@1343488 y_mf@1540096..3637248   (~16.2 MB)
// hd / pool staged in d_out (validated; rewritten by k_norm).

#define NG2  64
#define NPTS 4096

typedef unsigned short ushort_t;
typedef __attribute__((ext_vector_type(8))) short bf16x8;
typedef __attribute__((ext_vector_type(4))) float f32x4;

struct PrepPtrs { const void* p[16]; };

__device__ __forceinline__ float bf2f(ushort_t u) {
  return __uint_as_float(((unsigned int)u) << 16);
}
__device__ __forceinline__ ushort_t f2bf(float f) {
  __hip_bfloat16 b = __float2bfloat16(f);
  return *reinterpret_cast<ushort_t*>(&b);
}
__device__ __forceinline__ float lde(const void* p, size_t i, int fl) {
  return fl ? bf2f(((const ushort_t*)p)[i]) : ((const float*)p)[i];
}
__device__ __forceinline__ int block_flag(const ushort_t* h) {
  __shared__ int bad_sh;
  if (threadIdx.x == 0) bad_sh = 0;
  __syncthreads();
  float v = bf2f(h[threadIdx.x & 255]);
  if (!(fabsf(v) <= 1e4f)) atomicOr(&bad_sh, 1);
  __syncthreads();
  return (bad_sh == 0) ? 1 : 0;
}
// async 16B global->LDS (dest must be linear in tid order within the wave)
__device__ __forceinline__ void gload16(const ushort_t* g, ushort_t* l) {
  __builtin_amdgcn_global_load_lds(
      (const __attribute__((address_space(1))) unsigned int*)g,
      (__attribute__((address_space(3))) unsigned int*)l, 16, 0, 0);
}

// ---------------------------------------------------------------- prep (426 blocks)
// sections: [0,9)convert  [9,73)h2b  [73,137)tpWdec  [137,233)tpWout'
// [233,425)Xcat0  [425]stats0
__device__ __forceinline__ void tp_body(const void* in, int fl, int job,
                                        int Kin, int Kpad, ushort_t* out) {
  __shared__ ushort_t t[32][40];
  int n0 = (job & 31) * 32, k0 = (job >> 5) * 32;
  int r = threadIdx.x >> 3, c4 = (threadIdx.x & 7) * 4;
  ushort4 v = make_ushort4(0, 0, 0, 0);
  if (k0 + r < Kin) {
    size_t off = (size_t)(k0 + r) * 1024 + n0 + c4;
    if (fl) {
      v = *(const ushort4*)((const ushort_t*)in + off);
    } else {
      float4 f = *(const float4*)((const float*)in + off);
      v = make_ushort4(f2bf(f.x), f2bf(f.y), f2bf(f.z), f2bf(f.w));
    }
  }
  *(ushort4*)(&t[r][c4]) = v;
  __syncthreads();
  int n = threadIdx.x >> 3, kk = (threadIdx.x & 7) * 4;
  ushort4 o = make_ushort4(t[kk][n], t[kk + 1][n], t[kk + 2][n], t[kk + 3][n]);
  *(ushort4*)(out + (size_t)(n0 + n) * Kpad + k0 + kk) = o;
}

__global__ __launch_bounds__(256) void k_prep(PrepPtrs ptrs,
                                              float* __restrict__ conv,
                                              ushort_t* __restrict__ hbf,
                                              ushort_t* __restrict__ WdecT,
                                              ushort_t* __restrict__ WoutT,
                                              ushort_t* __restrict__ Xcat0,
                                              float* __restrict__ stats) {
  int b = blockIdx.x;
  int fl = block_flag((const ushort_t*)ptrs.p[0]);
  if (b < 9) {
    // 9 segments x 1024 floats: Wenc benc bdec wful bout bmlp gam bet w0
    int idx = (b * 256 + threadIdx.x) * 4;
    int seg = idx >> 10, off = idx & 1023;
    float4 o;
    if (fl) {
      const unsigned int* src = (const unsigned int*)ptrs.p[7 + seg];
      uint2 u = *(const uint2*)(src + (off >> 1));
      o.x = __uint_as_float((u.x & 0xFFFFu) << 16);
      o.y = __uint_as_float(u.x & 0xFFFF0000u);
      o.z = __uint_as_float((u.y & 0xFFFFu) << 16);
      o.w = __uint_as_float(u.y & 0xFFFF0000u);
    } else {
      o = *(const float4*)((const float*)ptrs.p[7 + seg] + off);
    }
    *(float4*)(conv + idx) = o;
  } else if (b < 73) {
    // h -> bf16, 16384 chunks of 8 elems, 64 blocks
    int i = (b - 9) * 256 + threadIdx.x;
    if (fl) {
      ((uint4*)hbf)[i] = ((const uint4*)ptrs.p[0])[i];
    } else {
      float4 f0 = ((const float4*)ptrs.p[0])[2 * i];
      float4 f1 = ((const float4*)ptrs.p[0])[2 * i + 1];
      ((ushort4*)hbf)[2 * i]     = make_ushort4(f2bf(f0.x), f2bf(f0.y), f2bf(f0.z), f2bf(f0.w));
      ((ushort4*)hbf)[2 * i + 1] = make_ushort4(f2bf(f1.x), f2bf(f1.y), f2bf(f1.z), f2bf(f1.w));
    }
  } else if (b < 137) {
    tp_body(ptrs.p[1], fl, b - 73, 64, 64, WdecT);
  } else if (b < 233) {
    const void* wout1 = fl ? (const void*)((const ushort_t*)ptrs.p[2] + 1024)
                           : (const void*)((const float*)ptrs.p[2] + 1024);
    tp_body(wout1, fl, b - 137, 68, 96, WoutT);
  } else if (b < 425) {
    int flat = (b - 233) * 256 + threadIdx.x;   // 49152 ushort4 items
    int e4 = flat * 4;
    int r = e4 / 96, c = e4 - r * 96;
    ushort4 v = make_ushort4(0, 0, 0, 0);
    if (c < 64) {
      if (fl) v = *(const ushort4*)((const ushort_t*)ptrs.p[0] + r * 64 + c);
      else {
        float4 f = *(const float4*)((const float*)ptrs.p[0] + r * 64 + c);
        v = make_ushort4(f2bf(f.x), f2bf(f.y), f2bf(f.z), f2bf(f.w));
      }
    } else if (c == 64) {
      v.x = f2bf(lde(ptrs.p[4], 2 * r, fl));      // end x
      v.y = f2bf(lde(ptrs.p[4], 2 * r + 1, fl));  // end y
      v.z = f2bf(lde(ptrs.p[5], 2 * r, fl));      // rel x
      v.w = f2bf(lde(ptrs.p[5], 2 * r + 1, fl));  // rel y
    }
    *(ushort4*)(Xcat0 + e4) = v;
  } else {
#pragma unroll
    for (int k = 0; k < 8; k++) stats[threadIdx.x + 256 * k] = 0.0f;
  }
}

// ---------------------------------------------------------------- MFMA GEMM body (64x128, gload_lds)
// EPI0: bf16(acc + b1 + b2) ; EPI3: f32 acc + b1
template <int K, int EPI>
__device__ __forceinline__ void mgemm_body(
    ushort_t* As, ushort_t* Bs, int m0, int n0,
    const ushort_t* __restrict__ A, int lda,
    const ushort_t* __restrict__ BT, int ldb,
    const float* __restrict__ bias1, const float* __restrict__ bias2,
    ushort_t* __restrict__ outb, float* __restrict__ outf) {
  int tid = threadIdx.x;
  int wave = tid >> 6, lane = tid & 63, l15 = lane & 15, kg = lane >> 4;
  f32x4 acc[4][2] = {};
  int ar = tid >> 2, ag = tid & 3;
  int agS = ag ^ ((ar >> 1) & 3);          // pre-swizzled global k-group
  int br1 = (tid + 256) >> 2, bg1 = (tid + 256) & 3;
  int bg1S = bg1 ^ ((br1 >> 1) & 3);
  for (int k0 = 0; k0 < K; k0 += 32) {
    gload16(A + (size_t)(m0 + ar) * lda + k0 + agS * 8, &As[tid * 8]);
    gload16(BT + (size_t)(n0 + ar) * ldb + k0 + agS * 8, &Bs[tid * 8]);
    gload16(BT + (size_t)(n0 + br1) * ldb + k0 + bg1S * 8, &Bs[(tid + 256) * 8]);
    __syncthreads();
    bf16x8 af[4], bfr[2];
#pragma unroll
    for (int mt = 0; mt < 4; mt++) {
      int row = mt * 16 + l15;
      int swz = kg ^ ((row >> 1) & 3);
      af[mt] = *(const bf16x8*)(&As[row * 32 + swz * 8]);
    }
#pragma unroll
    for (int nt = 0; nt < 2; nt++) {
      int row = wave * 32 + nt * 16 + l15;
      int swz = kg ^ ((row >> 1) & 3);
      bfr[nt] = *(const bf16x8*)(&Bs[row * 32 + swz * 8]);
    }
#pragma unroll
    for (int mt = 0; mt < 4; mt++)
#pragma unroll
      for (int nt = 0; nt < 2; nt++)
        acc[mt][nt] = __builtin_amdgcn_mfma_f32_16x16x32_bf16(af[mt], bfr[nt], acc[mt][nt], 0, 0, 0);
    __syncthreads();
  }
#pragma unroll
  for (int nt = 0; nt < 2; nt++) {
    int col = n0 + wave * 32 + nt * 16 + l15;
    float bsum = (EPI == 0) ? (bias1[col] + bias2[col]) : bias1[col];
#pragma unroll
    for (int mt = 0; mt < 4; mt++) {
#pragma unroll
      for (int r = 0; r < 4; r++) {
        int rowm = m0 + mt * 16 + kg * 4 + r;
        float v = acc[mt][nt][r] + bsum;
        if (EPI == 3) outf[(size_t)rowm * 1024 + col] = v;
        else outb[(size_t)rowm * 1024 + col] = f2bf(v);
      }
    }
  }
}

// ---------------------------------------------------------------- fused GEMM2 + occupancy + WmlpT
// [0,512) GEMM | [512,2560) occupancy ped | [2560,2816) WmlpT transpose.
__global__ __launch_bounds__(256) void k_fused(
    PrepPtrs ptrs,
    const ushort_t* __restrict__ hbf, const ushort_t* __restrict__ WdecT,
    const float* __restrict__ benc, const float* __restrict__ bdec,
    ushort_t* __restrict__ hd_out,
    const ushort_t* __restrict__ Xcat0, const ushort_t* __restrict__ WoutT,
    const float* __restrict__ bout, float* __restrict__ P1,
    ushort_t* __restrict__ WmlpT, float* __restrict__ occ) {
  __shared__ __align__(16) char smem_raw[12288];
  int b = blockIdx.x;
  if (b < 512) {
    ushort_t* As = (ushort_t*)smem_raw;              // 4096 B
    ushort_t* Bs = (ushort_t*)(smem_raw + 4096);     // 8192 B
    int bb = b & 255;
    int m0 = (bb & 31) * 64, n0 = ((bb >> 5) & 7) * 128;
    if (b < 256)
      mgemm_body<64, 0>(As, Bs, m0, n0, hbf, 64, WdecT, 64, benc, bdec, hd_out, nullptr);
    else
      mgemm_body<96, 3>(As, Bs, m0, n0, Xcat0, 96, WoutT, 96, bout, nullptr, nullptr, P1);
  } else if (b < 2560) {
    // occupancy: block per pedestrian; scene loads vectorized 2pts/load (r32)
    int fl = block_flag((const ushort_t*)ptrs.p[0]);
    int i = b - 512;
    int s = i >> 6;
    float* cnth = (float*)smem_raw;
    if (threadIdx.x < NG2) cnth[threadIdx.x] = 0.0f;
    __syncthreads();
    float ex = lde(ptrs.p[4], 2 * i, fl), ey = lde(ptrs.p[4], 2 * i + 1, fl);
    float tlx = ex - 1.0f, tly = ey + 1.0f, brx = ex + 1.0f, bry = ey - 1.0f;
    const void* scn = ptrs.p[6];
    for (int p2 = threadIdx.x; p2 < NPTS / 2; p2 += 256) {
      size_t pi = (size_t)s * (NPTS / 2) + p2;   // in 2-point units
      float sx0, sy0, sx1, sy1;
      if (fl) {
        uint2 u = ((const uint2*)scn)[pi];
        sx0 = __uint_as_float((u.x & 0xFFFFu) << 16);
        sy0 = __uint_as_float(u.x & 0xFFFF0000u);
        sx1 = __uint_as_float((u.y & 0xFFFFu) << 16);
        sy1 = __uint_as_float(u.y & 0xFFFF0000u);
      } else {
        float4 f = ((const float4*)scn)[pi];
        sx0 = f.x; sy0 = f.y; sx1 = f.z; sy1 = f.w;
      }
      bool oob0 = (sx0 >= brx) || (sx0 <= tlx) || (sy0 >= tly) || (sy0 <= bry);
      if (!oob0) {
        int cx = (int)floorf((sx0 - tlx) * 0.5f * 8.0f);
        int cy = (int)floorf((tly - sy0) * 0.5f * 8.0f);
        int cell = cx + cy * 8;
        if (cell >= 0 && cell < NG2) atomicAdd(&cnth[cell], 1.0f);
      }
      bool oob1 = (sx1 >= brx) || (sx1 <= tlx) || (sy1 >= tly) || (sy1 <= bry);
      if (!oob1) {
        int cx = (int)floorf((sx1 - tlx) * 0.5f * 8.0f);
        int cy = (int)floorf((tly - sy1) * 0.5f * 8.0f);
        int cell = cx + cy * 8;
        if (cell >= 0 && cell < NG2) atomicAdd(&cnth[cell], 1.0f);
      }
    }
    __syncthreads();
    if (threadIdx.x < NG2) occ[(size_t)i * NG2 + threadIdx.x] = cnth[threadIdx.x];
  } else {
    // W_mlp 1024x1024 -> WmlpT bf16, 64x64 tiles (r13-validated body)
    int fl = block_flag((const ushort_t*)ptrs.p[0]);
    ushort_t* t64 = (ushort_t*)smem_raw;             // 64*68*2 = 8704 B
    int job = b - 2560;
    int n0 = (job & 15) * 64, k0 = (job >> 4) * 64;
    const void* in = ptrs.p[3];
#pragma unroll
    for (int i = 0; i < 4; i++) {
      int chunk = threadIdx.x + i * 256;
      int r = chunk >> 4, c4 = (chunk & 15) * 4;
      ushort4 v;
      size_t off = (size_t)(k0 + r) * 1024 + n0 + c4;
      if (fl) {
        v = *(const ushort4*)((const ushort_t*)in + off);
      } else {
        float4 f = *(const float4*)((const float*)in + off);
        v = make_ushort4(f2bf(f.x), f2bf(f.y), f2bf(f.z), f2bf(f.w));
      }
      *(ushort4*)(&t64[r * 68 + c4]) = v;
    }
    __syncthreads();
#pragma unroll
    for (int i = 0; i < 4; i++) {
      int chunk = threadIdx.x + i * 256;
      int n = chunk >> 4, k4 = (chunk & 15) * 4;
      ushort4 o = make_ushort4(t64[(k4 + 0) * 68 + n], t64[(k4 + 1) * 68 + n],
                               t64[(k4 + 2) * 68 + n], t64[(k4 + 3) * 68 + n]);
      *(ushort4*)(WmlpT + (size_t)(n0 + n) * 1024 + k0 + k4) = o;
    }
  }
}

// ---------------------------------------------------------------- y GEMM 64x128 + gload_lds (r29 form)
__global__ __launch_bounds__(256) void k_ygemm(
    const ushort_t* __restrict__ A, const ushort_t* __restrict__ BT,
    const float* __restrict__ bias1, ushort_t* __restrict__ outb,
    float* __restrict__ stats) {
  __shared__ ushort_t As[64 * 32];
  __shared__ ushort_t Bs[128 * 32];
  int m0 = blockIdx.x * 64, n0 = blockIdx.y * 128;
  int tid = threadIdx.x;
  int wave = tid >> 6, lane = tid & 63, l15 = lane & 15, kg = lane >> 4;
  f32x4 acc[4][2] = {};
  int ar = tid >> 2, ag = tid & 3;
  int agS = ag ^ ((ar >> 1) & 3);
  int br1 = (tid + 256) >> 2, bg1 = (tid + 256) & 3;
  int bg1S = bg1 ^ ((br1 >> 1) & 3);
  for (int k0 = 0; k0 < 1024; k0 += 32) {
    gload16(A + (size_t)(m0 + ar) * 1024 + k0 + agS * 8, &As[tid * 8]);
    gload16(BT + (size_t)(n0 + ar) * 1024 + k0 + agS * 8, &Bs[tid * 8]);
    gload16(BT + (size_t)(n0 + br1) * 1024 + k0 + bg1S * 8, &Bs[(tid + 256) * 8]);
    __syncthreads();
    bf16x8 af[4], bfr[2];
#pragma unroll
    for (int mt = 0; mt < 4; mt++) {
      int row = mt * 16 + l15;
      int swz = kg ^ ((row >> 1) & 3);
      af[mt] = *(const bf16x8*)(&As[row * 32 + swz * 8]);
    }
#pragma unroll
    for (int nt = 0; nt < 2; nt++) {
      int row = wave * 32 + nt * 16 + l15;
      int swz = kg ^ ((row >> 1) & 3);
      bfr[nt] = *(const bf16x8*)(&Bs[row * 32 + swz * 8]);
    }
#pragma unroll
    for (int mt = 0; mt < 4; mt++)
#pragma unroll
      for (int nt = 0; nt < 2; nt++)
        acc[mt][nt] = __builtin_amdgcn_mfma_f32_16x16x32_bf16(af[mt], bfr[nt], acc[mt][nt], 0, 0, 0);
    __syncthreads();
  }
#pragma unroll
  for (int nt = 0; nt < 2; nt++) {
    int col = n0 + wave * 32 + nt * 16 + l15;
    float bsum = bias1[col];
    float s1 = 0.0f, s2 = 0.0f;
#pragma unroll
    for (int mt = 0; mt < 4; mt++) {
#pragma unroll
      for (int r = 0; r < 4; r++) {
        int rowm = m0 + mt * 16 + kg * 4 + r;
        float v = acc[mt][nt][r] + bsum;
        outb[(size_t)rowm * 1024 + col] = f2bf(v);
        s1 += v; s2 = fmaf(v, v, s2);
      }
    }
    s1 += __shfl_down(s1, 16); s2 += __shfl_down(s2, 16);
    s1 += __shfl_down(s1, 32); s2 += __shfl_down(s2, 32);
    if (lane < 16) {
      atomicAdd(&stats[col], s1);
      atomicAdd(&stats[1024 + col], s2);
    }
  }
}

// ---------------------------------------------------------------- ectx (shuffle-free e-phase)
__global__ __launch_bounds__(256) void k_ectx(
    const float* __restrict__ occ,
    const float* __restrict__ Wenc, const float* __restrict__ wfull,
    const float* __restrict__ w0, const float* __restrict__ P1,
    const ushort_t* __restrict__ hd, ushort_t* __restrict__ pool) {
  __shared__ float we_sh[1024];
  __shared__ float wf_sh[1024];
  __shared__ float hd_sh[4][1024];
  __shared__ float occ_sh[4][64];
  int wave = threadIdx.x >> 6, lane = threadIdx.x & 63;
  int p = blockIdx.x * 4 + wave;
  // cooperative stage of Wenc / wfull (256 threads x float4)
  {
    int t = threadIdx.x * 4;
    *(float4*)&we_sh[t] = *(const float4*)(Wenc + t);
    *(float4*)&wf_sh[t] = *(const float4*)(wfull + t);
  }
  occ_sh[wave][lane] = occ[p * 64 + lane];
  // stage hd row bf16 -> f32 (coalesced: 1KB per wave per j)
  {
    const ushort_t* hrow = hd + (size_t)p * 1024;
#pragma unroll
    for (int j = 0; j < 4; j++) {
      int a = lane * 4 + j * 256;
      ushort4 v = *(const ushort4*)(hrow + a);
      hd_sh[wave][a + 0] = bf2f(v.x);
      hd_sh[wave][a + 1] = bf2f(v.y);
      hd_sh[wave][a + 2] = bf2f(v.z);
      hd_sh[wave][a + 3] = bf2f(v.w);
    }
  }
  __syncthreads();
  // lane g = lane computes e[p,g] privately: broadcast LDS reads, no shuffles
  float c = occ_sh[wave][lane];
  float s0 = 0.0f, s1 = 0.0f, s2 = 0.0f, s3 = 0.0f;
#pragma unroll 4
  for (int a = 0; a < 1024; a += 4) {
    float4 we4 = *(const float4*)&we_sh[a];
    float4 hd4 = *(const float4*)&hd_sh[wave][a];
    float4 wf4 = *(const float4*)&wf_sh[a];
    s0 += fmaxf(fmaf(c, we4.x, hd4.x), 0.0f) * wf4.x;
    s1 += fmaxf(fmaf(c, we4.y, hd4.y), 0.0f) * wf4.y;
    s2 += fmaxf(fmaf(c, we4.z, hd4.z), 0.0f) * wf4.z;
    s3 += fmaxf(fmaf(c, we4.w, hd4.w), 0.0f) * wf4.w;
  }
  float e_mine = (s0 + s1) + (s2 + s3);
  // softmax over g (the only cross-lane phase left)
  float m = e_mine;
#pragma unroll
  for (int off = 32; off > 0; off >>= 1) m = fmaxf(m, __shfl_xor(m, off));
  float xe = __expf(e_mine - m);
  float den = xe;
#pragma unroll
  for (int off = 32; off > 0; off >>= 1) den += __shfl_xor(den, off);
  float cp = xe * c;
#pragma unroll
  for (int off = 32; off > 0; off >>= 1) cp += __shfl_xor(cp, off);
  float ctx = cp / den;
#pragma unroll
  for (int j = 0; j < 16; j++) {
    int a = lane + j * 64;
    pool[(size_t)p * 1024 + a] = f2bf(fmaf(ctx, w0[a], P1[(size_t)p * 1024 + a]));
  }
}

// ---------------------------------------------------------------- batchnorm+relu (validated)
__global__ void k_norm(const ushort_t* __restrict__ y_mf,
                       const float* __restrict__ stats,
                       const float* __restrict__ gamma, const float* __restrict__ beta,
                       const ushort_t* __restrict__ hsrc, void* __restrict__ out) {
  int fl = block_flag(hsrc);
  int idx = (blockIdx.x * 256 + threadIdx.x) * 4;
  int col = idx & 1023;
  float vv[4];
#pragma unroll
  for (int j = 0; j < 4; j++) vv[j] = bf2f(y_mf[idx + j]);
  float4 s1 = *(const float4*)(stats + col);
  float4 s2 = *(const float4*)(stats + 1024 + col);
  float4 gm = *(const float4*)(gamma + col);
  float4 bt = *(const float4*)(beta + col);
  const float ib = 1.0f / 2048.0f;
  float m1[4] = {s1.x, s1.y, s1.z, s1.w};
  float m2[4] = {s2.x, s2.y, s2.z, s2.w};
  float gg[4] = {gm.x, gm.y, gm.z, gm.w};
  float bb[4] = {bt.x, bt.y, bt.z, bt.w};
  float o[4];
#pragma unroll
  for (int j = 0; j < 4; j++) {
    float mu = m1[j] * ib;
    float var = fmaf(-mu, mu, m2[j] * ib);
    o[j] = fmaxf(fmaf(gg[j] * (vv[j] - mu), rsqrtf(var + 1e-5f), bb[j]), 0.0f);
  }
  if (fl) {
    ushort4 ov = make_ushort4(f2bf(o[0]), f2bf(o[1]), f2bf(o[2]), f2bf(o[3]));
    *(ushort4*)((ushort_t*)out + idx) = ov;
  } else {
    *(float4*)((float*)out + idx) = make_float4(o[0], o[1], o[2], o[3]);
  }
}

// ---------------------------------------------------------------- launch
extern "C" void kernel_launch(void* const* d_in, const int* in_sizes, int n_in,
                              void* d_out, int out_size, void* d_ws, size_t ws_size,
                              hipStream_t stream) {
  float* ws = (float*)d_ws;
  float* conv   = ws;
  float* c_Wenc = conv + 0;
  float* c_benc = conv + 1024;
  float* c_bdec = conv + 2048;
  float* c_wful = conv + 3072;
  float* c_bout = conv + 4096;
  float* c_bmlp = conv + 5120;
  float* c_gam  = conv + 6144;
  float* c_bet  = conv + 7168;
  float* c_w0   = conv + 8192;
  float* occ    = ws + 9216;
  float* stats  = ws + 140288;
  float* P1     = ws + 142336;
  ushort_t* u0    = (ushort_t*)(ws + 2239488);
  ushort_t* hbf   = u0;
  ushort_t* WdecT = u0 + 131072;
  ushort_t* WoutT = u0 + 196608;
  ushort_t* WmlpT = u0 + 294912;
  ushort_t* Xcat0 = u0 + 1343488;
  ushort_t* y_mf  = u0 + 1540096;
  ushort_t* hd_bf   = (ushort_t*)d_out;   // validated d_out-as-scratch
  ushort_t* pool_mf = (ushort_t*)d_out;

  PrepPtrs ptrs;
  ptrs.p[0] = d_in[0];   // h (flag, h2b, Xcat0)
  ptrs.p[1] = d_in[6];   // W_dec (tp)
  ptrs.p[2] = d_in[10];  // W_out (tp rows 1..68)
  ptrs.p[3] = d_in[12];  // W_mlp (tp 64x64, in k_fused)
  ptrs.p[4] = d_in[1];   // end_pos (Xcat0, occupancy)
  ptrs.p[5] = d_in[2];   // rel_pos (Xcat0)
  ptrs.p[6] = d_in[3];   // scene (occupancy)
  ptrs.p[7]  = d_in[4];  // W_enc  (conv seg0)
  ptrs.p[8]  = d_in[5];  // b_enc  (seg1)
  ptrs.p[9]  = d_in[7];  // b_dec  (seg2)
  ptrs.p[10] = d_in[8];  // w_full (seg3)
  ptrs.p[11] = d_in[11]; // b_out  (seg4)
  ptrs.p[12] = d_in[13]; // b_mlp  (seg5)
  ptrs.p[13] = d_in[14]; // gamma  (seg6)
  ptrs.p[14] = d_in[15]; // beta   (seg7)
  ptrs.p[15] = d_in[10]; // w0 = W_out row 0 (seg8)

  k_prep<<<426, 256, 0, stream>>>(ptrs, conv, hbf, WdecT, WoutT, Xcat0, stats);

  k_fused<<<2816, 256, 0, stream>>>(ptrs, hbf, WdecT, c_benc, c_bdec, hd_bf,
                                    Xcat0, WoutT, c_bout, P1, WmlpT, occ);

  k_ectx<<<512, 256, 0, stream>>>(occ, c_Wenc, c_wful, c_w0, P1, hd_bf, pool_mf);

  k_ygemm<<<dim3(32, 8), 256, 0, stream>>>(pool_mf, WmlpT, c_bmlp, y_mf, stats);

  k_norm<<<2048, 256, 0, stream>>>(y_mf, stats, c_gam, c_bet,
                                   (const ushort_t*)d_in[0], d_out);
}